// Round 9
// baseline (147.734 us; speedup 1.0000x reference)
//
#include <hip/hip_runtime.h>
#include <hip/hip_bf16.h>

// B=64, T=4096, Feat=32, Ch=16; kernel (3,32,1,16), Hp=14, Wp=1, F=16.
// out[bt,hp,f] = relu((conv + bias[f])*sc[t] + sh[t]),  t = bt % 4096
// conv[(bt,hp),f] = sum_{i<3,j<32} x[bt,j,hp+i] * k[i,j,f]
// R9: occupancy push 6->8 blocks/CU (32 waves/CU cap): LDS trimmed to
// exactly 20480B (16-row x-tiles, A-reads clamped min(hp+i,15) - clamped
// rows only feed discarded hp=14,15 columns), weights gathered per-lane
// from global (L2-hot) instead of LDS, __launch_bounds__(256,8) caps
// VGPR at 64. Swapped-operand MFMA + nt loads/stores as R8.

typedef __attribute__((ext_vector_type(8))) short bf16x8;
typedef __attribute__((ext_vector_type(4))) float f32x4;
typedef __attribute__((ext_vector_type(4))) unsigned int u32x4;

#define NBT 16               // bt tiles per block (4 waves * 4 bt)
#define XSTRIDE 40           // bf16 per xT row: 32 + 8 pad (80 B, 16B-aligned)
#define XTILE (16 * XSTRIDE)       // 640 bf16 = 1280 B per bt tile

__device__ __forceinline__ unsigned short f2bf(float f) {
    unsigned u = __builtin_bit_cast(unsigned, f);
    return (unsigned short)((u + 0x7fffu + ((u >> 16) & 1u)) >> 16);  // RNE
}
__device__ __forceinline__ unsigned pack2(float a, float b) {
    return (unsigned)f2bf(a) | ((unsigned)f2bf(b) << 16);
}

__global__ __launch_bounds__(256, 8) void tccnn_mfma(
    const float* __restrict__ x,      // (B*T, 32, 16)
    const float* __restrict__ kern,   // (3,32,1,16) = 1536
    const float* __restrict__ bias,   // (16,)
    const float* __restrict__ gamma,  // (4096,)
    const float* __restrict__ beta,   // (4096,)
    const float* __restrict__ mmean,  // (4096,)
    const float* __restrict__ mvar,   // (4096,)
    float* __restrict__ out)          // (B*T, 14, 16)
{
    __shared__ __align__(16) unsigned short xs[NBT * XTILE];    // 20480 B

    const int tid = threadIdx.x;
    const long bt0 = (long)blockIdx.x * NBT;

    // ---- stage x transposed: xT[c][j] bf16, 16 rows. Unit = 4c x 8j,
    //      1/thread, split into two 4j passes (4 nt loads + 4 b64 writes)
    //      to keep register pressure under the 64-VGPR occupancy cap. ----
    {
        const int u = tid & 15, btl_s = tid >> 4;
        const int cu = u & 3, ju = u >> 2;          // c0 = cu*4, j0 = ju*8
        const float* xbase = x + (bt0 + btl_s) * 512 + cu * 4;
        unsigned short* dst = &xs[btl_s * XTILE + ju * 8];
        #pragma unroll
        for (int p = 0; p < 2; ++p) {
            const int j0 = ju * 8 + p * 4;
            const f32x4* s4 = (const f32x4*)(xbase + j0 * 16);
            f32x4 r0 = __builtin_nontemporal_load(s4 + 0);
            f32x4 r1 = __builtin_nontemporal_load(s4 + 4);
            f32x4 r2 = __builtin_nontemporal_load(s4 + 8);
            f32x4 r3 = __builtin_nontemporal_load(s4 + 12);
            *(uint2*)&dst[(cu * 4 + 0) * XSTRIDE + p * 4] =
                make_uint2(pack2(r0.x, r1.x), pack2(r2.x, r3.x));
            *(uint2*)&dst[(cu * 4 + 1) * XSTRIDE + p * 4] =
                make_uint2(pack2(r0.y, r1.y), pack2(r2.y, r3.y));
            *(uint2*)&dst[(cu * 4 + 2) * XSTRIDE + p * 4] =
                make_uint2(pack2(r0.z, r1.z), pack2(r2.z, r3.z));
            *(uint2*)&dst[(cu * 4 + 3) * XSTRIDE + p * 4] =
                make_uint2(pack2(r0.w, r1.w), pack2(r2.w, r3.w));
        }
    }

    // ---- per-lane weight fragments gathered from global (L2-hot) ----
    const int lane = tid & 63;
    const int wv = tid >> 6;
    const int hp = lane & 15;                      // C col = hp; also f for A-op
    const int g = lane >> 4;                       // k-group; C rows f=g*4+r

    bf16x8 bfr[3];
    #pragma unroll
    for (int i = 0; i < 3; ++i) {
        const float* kb = kern + (i * 32 + g * 8) * 16 + hp;
        u32x4 w;
        #pragma unroll
        for (int jj = 0; jj < 4; ++jj)
            w[jj] = pack2(kb[(2 * jj) * 16], kb[(2 * jj + 1) * 16]);
        bfr[i] = __builtin_bit_cast(bf16x8, w);
    }
    const float4 b4 = *(const float4*)&bias[g * 4]; // bias[f], f = g*4+r

    __syncthreads();

    // ---- compute: wave owns 4 bts; 3 MFMAs each (swapped operands) ----
    const int row0 = hp * XSTRIDE + g * 8;                    // hp+0 <= 15
    const int row1 = (hp < 15 ? hp + 1 : 15) * XSTRIDE + g * 8;
    const int row2 = (hp < 14 ? hp + 2 : 15) * XSTRIDE + g * 8;

    #pragma unroll
    for (int q = 0; q < 4; ++q) {
        const int btl = wv * 4 + q;
        const unsigned short* xt = &xs[btl * XTILE];
        bf16x8 a0 = *(const bf16x8*)&xt[row0];
        bf16x8 a1 = *(const bf16x8*)&xt[row1];
        bf16x8 a2 = *(const bf16x8*)&xt[row2];

        f32x4 acc = {0.f, 0.f, 0.f, 0.f};
        acc = __builtin_amdgcn_mfma_f32_16x16x32_bf16(bfr[0], a0, acc, 0, 0, 0);
        acc = __builtin_amdgcn_mfma_f32_16x16x32_bf16(bfr[1], a1, acc, 0, 0, 0);
        acc = __builtin_amdgcn_mfma_f32_16x16x32_bf16(bfr[2], a2, acc, 0, 0, 0);

        const long bt = bt0 + btl;
        const int t = (int)(bt & 4095);
        const float sc = gamma[t] * rsqrtf(mvar[t] + 1e-3f);
        const float sh = beta[t] - mmean[t] * sc;

        if (hp < 14) {
            f32x4 y;
            y.x = fmaxf((acc[0] + b4.x) * sc + sh, 0.f);
            y.y = fmaxf((acc[1] + b4.y) * sc + sh, 0.f);
            y.z = fmaxf((acc[2] + b4.z) * sc + sh, 0.f);
            y.w = fmaxf((acc[3] + b4.w) * sc + sh, 0.f);
            __builtin_nontemporal_store(y, (f32x4*)(out + bt * 224 + hp * 16 + g * 4));
        }
    }
}

extern "C" void kernel_launch(void* const* d_in, const int* in_sizes, int n_in,
                              void* d_out, int out_size, void* d_ws, size_t ws_size,
                              hipStream_t stream) {
    const float* x     = (const float*)d_in[0];
    const float* kern  = (const float*)d_in[1];
    const float* bias  = (const float*)d_in[2];
    const float* gamma = (const float*)d_in[3];
    const float* beta  = (const float*)d_in[4];
    const float* mmean = (const float*)d_in[5];
    const float* mvar  = (const float*)d_in[6];
    float* out = (float*)d_out;

    const int n_bt = 64 * 4096;                    // 262144
    const int blocks = n_bt / NBT;                 // 16384
    tccnn_mfma<<<blocks, 256, 0, stream>>>(x, kern, bias, gamma, beta,
                                           mmean, mvar, out);
}

// Round 10
// 137.618 us; speedup vs baseline: 1.0735x; 1.0735x over previous
//
#include <hip/hip_runtime.h>
#include <hip/hip_bf16.h>

// B=64, T=4096, Feat=32, Ch=16; kernel (3,32,1,16), Hp=14, Wp=1, F=16.
// out[bt,hp,f] = relu((conv + bias[f])*sc[t] + sh[t]),  t = bt % 4096
// conv[(bt,hp),f] = sum_{i<3,j<32} x[bt,j,hp+i] * k[i,j,f]
// R10: isolate the occupancy lever (R9 confounded it with a strided weight
// gather, which regressed). R8 structure verbatim (LDS wsh staging, nt
// loads/stores, swapped-operand MFMA) but NBT=8: LDS 14976B + VGPR<=64
// (launch_bounds(256,8)) -> 8 blocks/CU = 32 waves/CU (was 6/24).

typedef __attribute__((ext_vector_type(8))) short bf16x8;
typedef __attribute__((ext_vector_type(4))) float f32x4;

#define NBT 8                // bt tiles per block (4 waves * 2 bt)
#define XSTRIDE 40           // bf16 per xT row: 32 + 8 pad (80 B, 16B-aligned)
#define XTILE (18 * XSTRIDE + 8)   // 728 bf16 per bt tile (rows 16,17 garbage,
                                   // feed only discarded hp=14,15 columns)
#define WSTRIDE 104          // bf16 per BwT row: 96 + 8 pad (208 B)

__device__ __forceinline__ unsigned short f2bf(float f) {
    unsigned u = __builtin_bit_cast(unsigned, f);
    return (unsigned short)((u + 0x7fffu + ((u >> 16) & 1u)) >> 16);  // RNE
}
__device__ __forceinline__ unsigned pack2(float a, float b) {
    return (unsigned)f2bf(a) | ((unsigned)f2bf(b) << 16);
}

__global__ __launch_bounds__(256, 8) void tccnn_mfma(
    const float* __restrict__ x,      // (B*T, 32, 16)
    const float* __restrict__ kern,   // (3,32,1,16) = 1536
    const float* __restrict__ bias,   // (16,)
    const float* __restrict__ gamma,  // (4096,)
    const float* __restrict__ beta,   // (4096,)
    const float* __restrict__ mmean,  // (4096,)
    const float* __restrict__ mvar,   // (4096,)
    float* __restrict__ out)          // (B*T, 14, 16)
{
    __shared__ __align__(16) unsigned short xs[NBT * XTILE];    // 11648 B
    __shared__ __align__(16) unsigned short wsh[16 * WSTRIDE];  // 3328 B

    const int tid = threadIdx.x;
    const long bt0 = (long)blockIdx.x * NBT;

    // ---- stage weights as BwT[f][k=i*32+j] bf16 (1536 floats, 6/thread) ----
    #pragma unroll
    for (int v = 0; v < 6; ++v) {
        int idx = v * 256 + tid;
        int ij = idx >> 4, f = idx & 15;
        wsh[f * WSTRIDE + ij] = f2bf(kern[idx]);
    }

    // ---- stage x transposed: xT[c][j] bf16. Unit = 4c x 4j; 256 units,
    //      1/thread: 4 nt float4 loads -> 4x ds_write_b64. ----
    {
        int U = tid;
        int btl = U >> 5, u = U & 31;
        int cu = u & 3, ju = u >> 2;              // c0 = cu*4, j0 = ju*4
        const f32x4* src = (const f32x4*)(x + (bt0 + btl) * 512 + ju * 64 + cu * 4);
        f32x4 r0 = __builtin_nontemporal_load(src + 0);
        f32x4 r1 = __builtin_nontemporal_load(src + 4);
        f32x4 r2 = __builtin_nontemporal_load(src + 8);
        f32x4 r3 = __builtin_nontemporal_load(src + 12);
        unsigned short* dst = &xs[btl * XTILE + ju * 4];
        *(uint2*)&dst[(cu * 4 + 0) * XSTRIDE] =
            make_uint2(pack2(r0.x, r1.x), pack2(r2.x, r3.x));
        *(uint2*)&dst[(cu * 4 + 1) * XSTRIDE] =
            make_uint2(pack2(r0.y, r1.y), pack2(r2.y, r3.y));
        *(uint2*)&dst[(cu * 4 + 2) * XSTRIDE] =
            make_uint2(pack2(r0.z, r1.z), pack2(r2.z, r3.z));
        *(uint2*)&dst[(cu * 4 + 3) * XSTRIDE] =
            make_uint2(pack2(r0.w, r1.w), pack2(r2.w, r3.w));
    }
    __syncthreads();

    // ---- compute: wave owns 2 bts; 3 MFMAs each (swapped operands) ----
    const int lane = tid & 63;
    const int wv = tid >> 6;
    const int hp = lane & 15;                      // C col = hp
    const int g = lane >> 4;                       // k-group; C rows f=g*4+r

    // A-operand (weights): lane provides BwT[f=lane&15][k=g*8+jj]
    bf16x8 bfr0 = *(const bf16x8*)&wsh[hp * WSTRIDE + 0 * 32 + g * 8];
    bf16x8 bfr1 = *(const bf16x8*)&wsh[hp * WSTRIDE + 1 * 32 + g * 8];
    bf16x8 bfr2 = *(const bf16x8*)&wsh[hp * WSTRIDE + 2 * 32 + g * 8];
    const float4 b4 = *(const float4*)&bias[g * 4]; // bias[f], f = g*4+r

    #pragma unroll
    for (int q = 0; q < 2; ++q) {
        const int btl = wv * 2 + q;
        const unsigned short* xt = &xs[btl * XTILE];
        // B-operand: lane provides xT[(lane&15)+i][k=g*8+jj]
        bf16x8 a0 = *(const bf16x8*)&xt[(hp + 0) * XSTRIDE + g * 8];
        bf16x8 a1 = *(const bf16x8*)&xt[(hp + 1) * XSTRIDE + g * 8];
        bf16x8 a2 = *(const bf16x8*)&xt[(hp + 2) * XSTRIDE + g * 8];

        f32x4 acc = {0.f, 0.f, 0.f, 0.f};
        acc = __builtin_amdgcn_mfma_f32_16x16x32_bf16(bfr0, a0, acc, 0, 0, 0);
        acc = __builtin_amdgcn_mfma_f32_16x16x32_bf16(bfr1, a1, acc, 0, 0, 0);
        acc = __builtin_amdgcn_mfma_f32_16x16x32_bf16(bfr2, a2, acc, 0, 0, 0);

        const long bt = bt0 + btl;
        const int t = (int)(bt & 4095);
        const float sc = gamma[t] * rsqrtf(mvar[t] + 1e-3f);
        const float sh = beta[t] - mmean[t] * sc;

        if (hp < 14) {
            f32x4 y;
            y.x = fmaxf((acc[0] + b4.x) * sc + sh, 0.f);
            y.y = fmaxf((acc[1] + b4.y) * sc + sh, 0.f);
            y.z = fmaxf((acc[2] + b4.z) * sc + sh, 0.f);
            y.w = fmaxf((acc[3] + b4.w) * sc + sh, 0.f);
            __builtin_nontemporal_store(y, (f32x4*)(out + bt * 224 + hp * 16 + g * 4));
        }
    }
}

extern "C" void kernel_launch(void* const* d_in, const int* in_sizes, int n_in,
                              void* d_out, int out_size, void* d_ws, size_t ws_size,
                              hipStream_t stream) {
    const float* x     = (const float*)d_in[0];
    const float* kern  = (const float*)d_in[1];
    const float* bias  = (const float*)d_in[2];
    const float* gamma = (const float*)d_in[3];
    const float* beta  = (const float*)d_in[4];
    const float* mmean = (const float*)d_in[5];
    const float* mvar  = (const float*)d_in[6];
    float* out = (float*)d_out;

    const int n_bt = 64 * 4096;                    // 262144
    const int blocks = n_bt / NBT;                 // 32768
    tccnn_mfma<<<blocks, 256, 0, stream>>>(x, kern, bias, gamma, beta,
                                           mmean, mvar, out);
}